// Round 1
// baseline (763.161 us; speedup 1.0000x reference)
//
#include <hip/hip_runtime.h>
#include <math.h>

#define N_INST 262144
#define G_PTS  1048576
#define BM 64
#define LDH 132   // 128 + 4 pad: stride ≡ 4 (mod 32 banks) -> conflict-free row access

// ---------------- device helpers ----------------

__device__ __forceinline__ void gemm_relu(const float* __restrict__ W,
                                          const float* __restrict__ bias,
                                          float (*h)[LDH], int t)
{
    // 64x128 = h(64x128) @ W(128x128), relu, in-place in LDS.
    // thread microtile: 8 rows x 4 cols.
    const int tc = (t & 31) * 4;   // col base (32 col-groups)
    const int tr = (t >> 5) * 8;   // row base (8 row-groups)

    float4 acc[8];
#pragma unroll
    for (int i = 0; i < 8; ++i) acc[i] = make_float4(0.f, 0.f, 0.f, 0.f);

    for (int kk = 0; kk < 128; kk += 4) {
        float4 hv[8];
#pragma unroll
        for (int i = 0; i < 8; ++i)
            hv[i] = *(const float4*)&h[tr + i][kk];   // broadcast across col-groups
#pragma unroll
        for (int j = 0; j < 4; ++j) {
            float4 wv = *(const float4*)&W[(kk + j) * 128 + tc]; // coalesced, L2-hot
#pragma unroll
            for (int i = 0; i < 8; ++i) {
                float hb = (j == 0) ? hv[i].x : (j == 1) ? hv[i].y
                         : (j == 2) ? hv[i].z : hv[i].w;
                acc[i].x = fmaf(hb, wv.x, acc[i].x);
                acc[i].y = fmaf(hb, wv.y, acc[i].y);
                acc[i].z = fmaf(hb, wv.z, acc[i].z);
                acc[i].w = fmaf(hb, wv.w, acc[i].w);
            }
        }
    }

    float4 bv = *(const float4*)&bias[tc];
    __syncthreads();   // all reads of h done before anyone overwrites
#pragma unroll
    for (int i = 0; i < 8; ++i) {
        float4 r;
        r.x = fmaxf(acc[i].x + bv.x, 0.f);
        r.y = fmaxf(acc[i].y + bv.y, 0.f);
        r.z = fmaxf(acc[i].z + bv.z, 0.f);
        r.w = fmaxf(acc[i].w + bv.w, 0.f);
        *(float4*)&h[tr + i][tc] = r;
    }
    __syncthreads();   // writes visible
}

__device__ __forceinline__ void layer_norm(const float* __restrict__ g,
                                           const float* __restrict__ b,
                                           float (*h)[LDH], int t)
{
    // 4 consecutive lanes own one row (32 elems each); shuffle-reduce width 4.
    const int r = t >> 2, j = t & 3;
    const int cbase = j * 32;

    float4 v[8];
    float sum = 0.f, ssq = 0.f;
#pragma unroll
    for (int i = 0; i < 8; ++i) {
        v[i] = *(const float4*)&h[r][cbase + i * 4];
        sum += v[i].x + v[i].y + v[i].z + v[i].w;
        ssq += v[i].x * v[i].x + v[i].y * v[i].y + v[i].z * v[i].z + v[i].w * v[i].w;
    }
    sum += __shfl_xor(sum, 1); sum += __shfl_xor(sum, 2);
    ssq += __shfl_xor(ssq, 1); ssq += __shfl_xor(ssq, 2);

    const float mu  = sum * (1.0f / 128.0f);
    const float var = ssq * (1.0f / 128.0f) - mu * mu;
    const float rs  = rsqrtf(var + 1e-5f);

#pragma unroll
    for (int i = 0; i < 8; ++i) {
        float4 gv = *(const float4*)&g[cbase + i * 4];
        float4 bv = *(const float4*)&b[cbase + i * 4];
        float4 o;
        o.x = (v[i].x - mu) * rs * gv.x + bv.x;
        o.y = (v[i].y - mu) * rs * gv.y + bv.y;
        o.z = (v[i].z - mu) * rs * gv.z + bv.z;
        o.w = (v[i].w - mu) * rs * gv.w + bv.w;
        *(float4*)&h[r][cbase + i * 4] = o;   // thread-exclusive elements
    }
    __syncthreads();
}

// ---------------- kernels ----------------

__global__ __launch_bounds__(64) void zero_kernel(float* p)
{
    if (threadIdx.x == 0) p[0] = 0.0f;
}

__global__ __launch_bounds__(256) void mlp_kernel(
    const float* __restrict__ instf, const float* __restrict__ aemb,
    const float* __restrict__ anchor,
    const float* __restrict__ w1, const float* __restrict__ b1,
    const float* __restrict__ w2, const float* __restrict__ b2,
    const float* __restrict__ ln1g, const float* __restrict__ ln1b,
    const float* __restrict__ w3, const float* __restrict__ b3,
    const float* __restrict__ w4, const float* __restrict__ b4,
    const float* __restrict__ ln2g, const float* __restrict__ ln2b,
    const float* __restrict__ w5, const float* __restrict__ b5,
    const float* __restrict__ scale,
    float* __restrict__ stash, float* __restrict__ dacc)
{
    __shared__ float h[BM][LDH];      // 33.8 KB
    __shared__ float w5c[128][4];     // the only 4 w5 columns that matter: 0,1,2,10
    __shared__ float redbuf[4];

    const int t = threadIdx.x;
    const int blockRow = blockIdx.x * BM;

    // ---- x = instance_feature + anchor_embed -> LDS ----
    {
        const int base = blockRow * 128;
#pragma unroll
        for (int it = 0; it < 8; ++it) {
            int flat = it * 1024 + t * 4;
            int row = flat >> 7, col = flat & 127;
            float4 a = *(const float4*)&instf[base + flat];
            float4 e = *(const float4*)&aemb[base + flat];
            float4 s;
            s.x = a.x + e.x; s.y = a.y + e.y; s.z = a.z + e.z; s.w = a.w + e.w;
            *(float4*)&h[row][col] = s;
        }
    }
    // stage w5 columns {0,1,2,10}
    for (int p = t; p < 512; p += 256) {
        int k = p >> 2, j = p & 3;
        int jc = (j < 3) ? j : 10;
        w5c[k][j] = w5[k * 86 + jc];
    }
    __syncthreads();

    gemm_relu(w1, b1, h, t);
    gemm_relu(w2, b2, h, t);
    layer_norm(ln1g, ln1b, h, t);
    gemm_relu(w3, b3, h, t);
    gemm_relu(w4, b4, h, t);
    layer_norm(ln2g, ln2b, h, t);

    // ---- projection to cols {0,1,2,10}, sigmoid, stash, global reduction ----
    {
        const int r = t >> 2, j = t & 3;
        const int jcol = (j < 3) ? j : 10;
        const int grow = blockRow + r;

        float acc = 0.f;
#pragma unroll 8
        for (int k = 0; k < 128; ++k)
            acc = fmaf(h[r][k], w5c[k][j], acc);

        float outv = (acc + b5[jcol]) * scale[jcol] + anchor[grow * 86 + jcol];
        float xc  = fminf(fmaxf(outv, -9.21f), 9.21f);
        float sig = 1.0f / (1.0f + expf(-xc));

        stash[grow * 4 + j] = sig;    // coalesced: blockRow*4 + t

        float inv = (j < 3) ? (1.0f / sig) : 0.0f;
#pragma unroll
        for (int off = 32; off > 0; off >>= 1)
            inv += __shfl_down(inv, off);
        if ((t & 63) == 0) redbuf[t >> 6] = inv;
        __syncthreads();
        if (t == 0)
            atomicAdd(dacc, (redbuf[0] + redbuf[1]) + (redbuf[2] + redbuf[3]));
    }
}

__global__ __launch_bounds__(256) void finalize_kernel(
    const float* __restrict__ stash, const float* __restrict__ dacc,
    const float* __restrict__ means, const float* __restrict__ opac,
    const int* __restrict__ idxs,
    float* __restrict__ out_means, float* __restrict__ out_opac)
{
    const int row = blockIdx.x * 256 + threadIdx.x;
    if (row >= N_INST) return;

    const float s  = dacc[0];
    const float d  = 1.0f / s;
    const float dm = fmaxf(d, 1e-8f);
    // offsets = (xyz / dm) * (exp(d - 6) - exp(-6))
    const float coef = (expf(d - 6.0f) - expf(-6.0f)) / dm;

    float4 st = *(const float4*)&stash[row * 4];   // {sig_x, sig_y, sig_z, sig_opa}
    const int idx = idxs[row];                     // unique (permutation slice)

    out_means[idx * 3 + 0] = means[idx * 3 + 0] + st.x * coef;
    out_means[idx * 3 + 1] = means[idx * 3 + 1] + st.y * coef;
    out_means[idx * 3 + 2] = means[idx * 3 + 2] + st.z * coef;
    out_opac[idx] = opac[idx] + 0.05f * st.w;
}

// ---------------- launch ----------------

extern "C" void kernel_launch(void* const* d_in, const int* in_sizes, int n_in,
                              void* d_out, int out_size, void* d_ws, size_t ws_size,
                              hipStream_t stream)
{
    const float* instf  = (const float*)d_in[0];
    const float* anchor = (const float*)d_in[1];
    const float* aemb   = (const float*)d_in[2];
    const float* means  = (const float*)d_in[3];
    const float* opac   = (const float*)d_in[4];
    const float* w1  = (const float*)d_in[5];  const float* b1  = (const float*)d_in[6];
    const float* w2  = (const float*)d_in[7];  const float* b2  = (const float*)d_in[8];
    const float* ln1g= (const float*)d_in[9];  const float* ln1b= (const float*)d_in[10];
    const float* w3  = (const float*)d_in[11]; const float* b3  = (const float*)d_in[12];
    const float* w4  = (const float*)d_in[13]; const float* b4  = (const float*)d_in[14];
    const float* ln2g= (const float*)d_in[15]; const float* ln2b= (const float*)d_in[16];
    const float* w5  = (const float*)d_in[17]; const float* b5  = (const float*)d_in[18];
    const float* scale = (const float*)d_in[19];
    const int*   idxs  = (const int*)d_in[20];

    float* out_means = (float*)d_out;
    float* out_opac  = out_means + (size_t)3 * G_PTS;

    float* dacc  = (float*)d_ws;            // 1 float accumulator
    float* stash = (float*)d_ws + 16;       // N*4 floats, 64B-offset

    zero_kernel<<<1, 64, 0, stream>>>(dacc);

    mlp_kernel<<<N_INST / BM, 256, 0, stream>>>(
        instf, aemb, anchor,
        w1, b1, w2, b2, ln1g, ln1b,
        w3, b3, w4, b4, ln2g, ln2b,
        w5, b5, scale, stash, dacc);

    // means/opacities passthrough (scatter overwrites the touched 25% afterwards)
    hipMemcpyAsync(out_means, means, (size_t)3 * G_PTS * sizeof(float),
                   hipMemcpyDeviceToDevice, stream);
    hipMemcpyAsync(out_opac, opac, (size_t)G_PTS * sizeof(float),
                   hipMemcpyDeviceToDevice, stream);

    finalize_kernel<<<N_INST / 256, 256, 0, stream>>>(
        stash, dacc, means, opac, idxs, out_means, out_opac);
}

// Round 6
// 475.748 us; speedup vs baseline: 1.6041x; 1.6041x over previous
//
#include <hip/hip_runtime.h>
#include <math.h>

#define N_INST 262144
#define G_PTS  1048576

typedef __attribute__((ext_vector_type(8))) short short8;
typedef __attribute__((ext_vector_type(4))) float f32x4;

__device__ __forceinline__ float bf2f(unsigned short u) {
    union { unsigned int i; float f; } v; v.i = ((unsigned int)u) << 16; return v.f;
}
__device__ __forceinline__ unsigned short f2bf(float f) {
    union { float f; unsigned int i; } v; v.f = f;
    unsigned int u = v.i;
    return (unsigned short)((u + 0x7fffu + ((u >> 16) & 1u)) >> 16);
}

// ---------------- weight pre-pack: fp32 W[k][n] -> per-lane bf16 B-fragments ----
// frag layout for v_mfma_f32_16x16x32_bf16 B operand:
//   lane l holds B[k = kt*32 + (l>>4)*8 + e][n = ct*16 + (l&15)], e=0..7
__global__ __launch_bounds__(64) void prepack_kernel(
    const float* __restrict__ w1, const float* __restrict__ w2,
    const float* __restrict__ w3, const float* __restrict__ w4,
    unsigned short* __restrict__ wp)
{
    const int bid = blockIdx.x;                  // L*32 + kt*8 + ct
    const int L = bid >> 5, kt = (bid >> 3) & 3, ct = bid & 7;
    const float* W = (L == 0) ? w1 : (L == 1) ? w2 : (L == 2) ? w3 : w4;
    const int l  = threadIdx.x;
    const int k0 = kt * 32 + (l >> 4) * 8;
    const int n  = ct * 16 + (l & 15);
    unsigned short* dst = wp + ((size_t)bid * 64 + l) * 8;
#pragma unroll
    for (int e = 0; e < 8; ++e)
        dst[e] = f2bf(W[(k0 + e) * 128 + n]);
}

__global__ __launch_bounds__(64) void zero_kernel(float* p)
{
    if (threadIdx.x == 0) p[0] = 0.0f;
}

// h LDS layout: 64 rows x 16 chunks of 8 bf16; chunk c stored at (c ^ (row&7)).
__device__ __forceinline__ void gemm_relu_mfma(
    const unsigned short* __restrict__ wp, int L,
    const float* __restrict__ bias, short* hl, int l, int wv)
{
    const short8* wp8 = (const short8*)wp;
    short8 bfrag[4][2];
#pragma unroll
    for (int kt = 0; kt < 4; ++kt)
#pragma unroll
        for (int cw = 0; cw < 2; ++cw)
            bfrag[kt][cw] = wp8[((L * 4 + kt) * 8 + (wv * 2 + cw)) * 64 + l];

    f32x4 acc[4][2];
#pragma unroll
    for (int rt = 0; rt < 4; ++rt)
#pragma unroll
        for (int cw = 0; cw < 2; ++cw)
            acc[rt][cw] = (f32x4)(0.0f);

    const short8* h8 = (const short8*)hl;
#pragma unroll
    for (int kt = 0; kt < 4; ++kt) {
        short8 afrag[4];
#pragma unroll
        for (int rt = 0; rt < 4; ++rt) {
            int row = rt * 16 + (l & 15);
            int c   = kt * 4 + (l >> 4);
            afrag[rt] = h8[row * 16 + (c ^ (row & 7))];
        }
#pragma unroll
        for (int rt = 0; rt < 4; ++rt)
#pragma unroll
            for (int cw = 0; cw < 2; ++cw)
                acc[rt][cw] = __builtin_amdgcn_mfma_f32_16x16x32_bf16(
                    afrag[rt], bfrag[kt][cw], acc[rt][cw], 0, 0, 0);
    }
    __syncthreads();   // all A-reads of h done before overwrite

#pragma unroll
    for (int cw = 0; cw < 2; ++cw) {
        int col = wv * 32 + cw * 16 + (l & 15);
        float bv = bias[col];
        int cc = col >> 3;
#pragma unroll
        for (int rt = 0; rt < 4; ++rt) {
#pragma unroll
            for (int r = 0; r < 4; ++r) {
                int row = rt * 16 + (l >> 4) * 4 + r;
                float v = fmaxf(acc[rt][cw][r] + bv, 0.f);
                hl[row * 128 + ((cc ^ (row & 7)) * 8) + (col & 7)] = (short)f2bf(v);
            }
        }
    }
    __syncthreads();
}

__device__ __forceinline__ void layer_norm_bf(
    const float* __restrict__ g, const float* __restrict__ b, short* hl, int t)
{
    const int r = t >> 2, j = t & 3;
    const short8* h8 = (const short8*)hl;
    float f[32];
    float sum = 0.f, ssq = 0.f;
#pragma unroll
    for (int i = 0; i < 4; ++i) {
        int cc = j * 4 + i;
        short8 v = h8[r * 16 + (cc ^ (r & 7))];
#pragma unroll
        for (int e = 0; e < 8; ++e) {
            float x = bf2f((unsigned short)v[e]);
            f[i * 8 + e] = x;
            sum += x; ssq += x * x;
        }
    }
    sum += __shfl_xor(sum, 1); sum += __shfl_xor(sum, 2);
    ssq += __shfl_xor(ssq, 1); ssq += __shfl_xor(ssq, 2);
    const float mu  = sum * (1.0f / 128.0f);
    const float var = ssq * (1.0f / 128.0f) - mu * mu;
    const float rs  = rsqrtf(var + 1e-5f);
#pragma unroll
    for (int i = 0; i < 4; ++i) {
        int cc = j * 4 + i;
        short8 s;
#pragma unroll
        for (int e = 0; e < 8; ++e) {
            int k = cc * 8 + e;
            float o = (f[i * 8 + e] - mu) * rs * g[k] + b[k];
            s[e] = (short)f2bf(o);
        }
        ((short8*)hl)[r * 16 + (cc ^ (r & 7))] = s;
    }
    __syncthreads();
}

__global__ __launch_bounds__(256) void mlp_kernel(
    const float* __restrict__ instf, const float* __restrict__ aemb,
    const float* __restrict__ anchor,
    const unsigned short* __restrict__ wp,
    const float* __restrict__ b1, const float* __restrict__ b2,
    const float* __restrict__ ln1g, const float* __restrict__ ln1b,
    const float* __restrict__ b3, const float* __restrict__ b4,
    const float* __restrict__ ln2g, const float* __restrict__ ln2b,
    const float* __restrict__ w5, const float* __restrict__ b5,
    const float* __restrict__ scale,
    float* __restrict__ stash, float* __restrict__ dacc)
{
    __shared__ short hl[64 * 128];     // 16 KB, bf16 bits, swizzled 16B chunks
    __shared__ float w5c[128][4];      // w5 cols {0,1,2,10}
    __shared__ float redbuf[4];

    const int t  = threadIdx.x;
    const int l  = t & 63;
    const int wv = t >> 6;
    const int blockRow = blockIdx.x * 64;

    // ---- stage x = instf + aemb -> bf16 swizzled LDS ----
    {
        const size_t base = (size_t)blockRow * 128;
#pragma unroll
        for (int it = 0; it < 4; ++it) {
            int id  = it * 256 + t;
            int row = id >> 4, c = id & 15;
            const float* pa = instf + base + row * 128 + c * 8;
            const float* pe = aemb  + base + row * 128 + c * 8;
            f32x4 a0 = *(const f32x4*)pa, a1 = *(const f32x4*)(pa + 4);
            f32x4 e0 = *(const f32x4*)pe, e1 = *(const f32x4*)(pe + 4);
            short8 s;
            s[0] = (short)f2bf(a0.x + e0.x); s[1] = (short)f2bf(a0.y + e0.y);
            s[2] = (short)f2bf(a0.z + e0.z); s[3] = (short)f2bf(a0.w + e0.w);
            s[4] = (short)f2bf(a1.x + e1.x); s[5] = (short)f2bf(a1.y + e1.y);
            s[6] = (short)f2bf(a1.z + e1.z); s[7] = (short)f2bf(a1.w + e1.w);
            ((short8*)hl)[row * 16 + (c ^ (row & 7))] = s;
        }
    }
    for (int p = t; p < 512; p += 256) {
        int k = p >> 2, j = p & 3;
        int jc = (j < 3) ? j : 10;
        w5c[k][j] = w5[k * 86 + jc];
    }
    __syncthreads();

    gemm_relu_mfma(wp, 0, b1, hl, l, wv);
    gemm_relu_mfma(wp, 1, b2, hl, l, wv);
    layer_norm_bf(ln1g, ln1b, hl, t);
    gemm_relu_mfma(wp, 2, b3, hl, l, wv);
    gemm_relu_mfma(wp, 3, b4, hl, l, wv);
    layer_norm_bf(ln2g, ln2b, hl, t);

    // ---- projection to cols {0,1,2,10} + sigmoid + reduction ----
    {
        const int r = t >> 2, j = t & 3;
        const int jc = (j < 3) ? j : 10;
        const int grow = blockRow + r;
        const short8* h8 = (const short8*)hl;

        float acc = 0.f;
#pragma unroll
        for (int cc = 0; cc < 16; ++cc) {
            short8 v = h8[r * 16 + (cc ^ (r & 7))];
#pragma unroll
            for (int e = 0; e < 8; ++e)
                acc = fmaf(bf2f((unsigned short)v[e]), w5c[cc * 8 + e][j], acc);
        }

        float outv = (acc + b5[jc]) * scale[jc] + anchor[(size_t)grow * 86 + jc];
        float xc  = fminf(fmaxf(outv, -9.21f), 9.21f);
        float sig = 1.0f / (1.0f + expf(-xc));

        stash[(size_t)grow * 4 + j] = sig;

        float inv = (j < 3) ? (1.0f / sig) : 0.0f;
#pragma unroll
        for (int off = 32; off > 0; off >>= 1)
            inv += __shfl_down(inv, off);
        if ((t & 63) == 0) redbuf[t >> 6] = inv;
        __syncthreads();
        if (t == 0)
            atomicAdd(dacc, (redbuf[0] + redbuf[1]) + (redbuf[2] + redbuf[3]));
    }
}

// passthrough copy of means+opacities as one coalesced float4 kernel
__global__ __launch_bounds__(256) void copy_kernel(
    const float* __restrict__ means, const float* __restrict__ opac,
    float* __restrict__ om, float* __restrict__ oo)
{
    const int i = blockIdx.x * 256 + threadIdx.x;      // 0 .. 1048575
    const int NM4 = 3 * G_PTS / 4;                     // 786432 float4s of means
    if (i < NM4) {
        ((f32x4*)om)[i] = ((const f32x4*)means)[i];
    } else {
        int k = i - NM4;                               // 0 .. 262143
        ((f32x4*)oo)[k] = ((const f32x4*)opac)[k];
    }
}

__global__ __launch_bounds__(256) void finalize_kernel(
    const float* __restrict__ stash, const float* __restrict__ dacc,
    const float* __restrict__ means, const float* __restrict__ opac,
    const int* __restrict__ idxs,
    float* __restrict__ out_means, float* __restrict__ out_opac)
{
    const int row = blockIdx.x * 256 + threadIdx.x;
    if (row >= N_INST) return;

    const float s  = dacc[0];
    const float d  = 1.0f / s;
    const float dm = fmaxf(d, 1e-8f);
    const float coef = (expf(d - 6.0f) - expf(-6.0f)) / dm;

    f32x4 st = *(const f32x4*)&stash[(size_t)row * 4];
    const int idx = idxs[row];

    out_means[idx * 3 + 0] = means[idx * 3 + 0] + st.x * coef;
    out_means[idx * 3 + 1] = means[idx * 3 + 1] + st.y * coef;
    out_means[idx * 3 + 2] = means[idx * 3 + 2] + st.z * coef;
    out_opac[idx] = opac[idx] + 0.05f * st.w;
}

// ---------------- launch ----------------

extern "C" void kernel_launch(void* const* d_in, const int* in_sizes, int n_in,
                              void* d_out, int out_size, void* d_ws, size_t ws_size,
                              hipStream_t stream)
{
    const float* instf  = (const float*)d_in[0];
    const float* anchor = (const float*)d_in[1];
    const float* aemb   = (const float*)d_in[2];
    const float* means  = (const float*)d_in[3];
    const float* opac   = (const float*)d_in[4];
    const float* w1  = (const float*)d_in[5];  const float* b1  = (const float*)d_in[6];
    const float* w2  = (const float*)d_in[7];  const float* b2  = (const float*)d_in[8];
    const float* ln1g= (const float*)d_in[9];  const float* ln1b= (const float*)d_in[10];
    const float* w3  = (const float*)d_in[11]; const float* b3  = (const float*)d_in[12];
    const float* w4  = (const float*)d_in[13]; const float* b4  = (const float*)d_in[14];
    const float* ln2g= (const float*)d_in[15]; const float* ln2b= (const float*)d_in[16];
    const float* w5  = (const float*)d_in[17]; const float* b5  = (const float*)d_in[18];
    const float* scale = (const float*)d_in[19];
    const int*   idxs  = (const int*)d_in[20];

    float* out_means = (float*)d_out;
    float* out_opac  = out_means + (size_t)3 * G_PTS;

    float*          dacc  = (float*)d_ws;
    float*          stash = (float*)((char*)d_ws + 256);
    unsigned short* wpack = (unsigned short*)((char*)d_ws + 256 + (size_t)4 * N_INST * sizeof(float));

    zero_kernel<<<1, 64, 0, stream>>>(dacc);
    prepack_kernel<<<128, 64, 0, stream>>>(w1, w2, w3, w4, wpack);

    mlp_kernel<<<N_INST / 64, 256, 0, stream>>>(
        instf, aemb, anchor, wpack,
        b1, b2, ln1g, ln1b, b3, b4, ln2g, ln2b,
        w5, b5, scale, stash, dacc);

    copy_kernel<<<G_PTS / 256, 256, 0, stream>>>(means, opac, out_means, out_opac);

    finalize_kernel<<<N_INST / 256, 256, 0, stream>>>(
        stash, dacc, means, opac, idxs, out_means, out_opac);
}